// Round 9
// baseline (462.682 us; speedup 1.0000x reference)
//
#include <hip/hip_runtime.h>

// Problem constants (from reference setup_inputs)
#define B_   4
#define T_   1024
#define E_   4
#define C_   512
#define IN_  2048
#define OUT_ 8192
#define EI_  512   // expert in-features = IN_/E_

typedef float f32x4 __attribute__((ext_vector_type(4)));
typedef __bf16 bf16x8 __attribute__((ext_vector_type(8)));
typedef unsigned short ushort8 __attribute__((ext_vector_type(8)));

__device__ __forceinline__ unsigned short f32_bf16(float f) {
  unsigned int u = __float_as_uint(f);
  u += 0x7FFFu + ((u >> 16) & 1u);   // round-to-nearest-even (finite inputs)
  return (unsigned short)(u >> 16);
}

__device__ __forceinline__ void gl2lds16(const void* g, void* l) {
  __builtin_amdgcn_global_load_lds(
      (const __attribute__((address_space(1))) void*)g,
      (__attribute__((address_space(3))) void*)l, 16, 0, 0);
}

#define DSR(dst, addr) do { f32x4 _t_; \
    asm volatile("ds_read_b128 %0, %1" : "=v"(_t_) : "v"(addr)); \
    dst = __builtin_bit_cast(bf16x8, _t_); } while (0)

// ---------------------------------------------------------------------------
// Fused prep: one launch, three independent jobs selected by blockIdx range.
// ---------------------------------------------------------------------------
__global__ __launch_bounds__(256)
void prep(const float* __restrict__ xsrc, const float* __restrict__ msrc,
          const float* __restrict__ combine, const float* __restrict__ weight,
          unsigned short* __restrict__ xdst, unsigned short* __restrict__ mdst,
          unsigned short* __restrict__ comb_bf, float* __restrict__ S,
          unsigned short* __restrict__ W2) {
  const int bid = blockIdx.x;
  const int u = threadIdx.x;
  if (bid < 4096) {
    __shared__ float tile[64][65];
    const int z = bid >> 9;             // 0..7
    const int which = z >> 2;
    const int b = z & 3;
    const int rem = bid & 511;
    const int t0 = (rem >> 5) * 64;
    const int k0 = (rem & 31) * 64;
    const float* src = which ? msrc : xsrc;
    unsigned short* dst = which ? mdst : xdst;
    const int lrow = u >> 4;
    const int lcol = (u & 15) * 4;
    const float* s = src + (size_t)b * (T_ * 2048) + (size_t)t0 * 2048 + k0;
#pragma unroll
    for (int r = 0; r < 4; r++) {
      float4 v = *(const float4*)(s + (size_t)(lrow + 16 * r) * 2048 + lcol);
      tile[lrow + 16 * r][lcol]     = v.x;
      tile[lrow + 16 * r][lcol + 1] = v.y;
      tile[lrow + 16 * r][lcol + 2] = v.z;
      tile[lrow + 16 * r][lcol + 3] = v.w;
    }
    __syncthreads();
    const int kr = u >> 2;
    const int tq = (u & 3) * 8;
    const int kg = k0 + kr;
    const int e  = kg >> 9;
    const int kl = kg & 511;
    unsigned short* d = dst + (((size_t)b * 4 + e) * 512 + kl) * 1024 + t0 + tq;
#pragma unroll
    for (int s8 = 0; s8 < 2; s8++) {
      ushort8 rr;
#pragma unroll
      for (int j = 0; j < 8; j++) rr[j] = f32_bf16(tile[tq + s8 * 32 + j][kr]);
      *(ushort8*)(d + s8 * 32) = rr;
    }
  } else if (bid < 8192) {
    __shared__ float red[256];
    const int row = bid - 4096;
    const float4* p = (const float4*)(combine + (size_t)row * 2048) + (size_t)u * 2;
    float4 a = p[0], b = p[1];
    ushort8 r;
    r[0] = f32_bf16(a.x); r[1] = f32_bf16(a.y);
    r[2] = f32_bf16(a.z); r[3] = f32_bf16(a.w);
    r[4] = f32_bf16(b.x); r[5] = f32_bf16(b.y);
    r[6] = f32_bf16(b.z); r[7] = f32_bf16(b.w);
    *((ushort8*)(comb_bf + (size_t)row * 2048) + u) = r;
    float s = (a.x + a.y + a.z + a.w) + (b.x + b.y + b.z + b.w);
    red[u] = s;
    __syncthreads();
#pragma unroll
    for (int st = 128; st > 0; st >>= 1) {
      if (u < st) red[u] += red[u + st];
      __syncthreads();
    }
    if (u == 0) S[row] = red[0];
  } else {
    const int tid = (bid - 8192) * 256 + u;
    const int i8 = tid & 63;
    const int e  = (tid >> 6) & 3;
    const int o  = tid >> 8;
    const float* s = weight + (size_t)e * 4194304 + (size_t)o * 512 + i8 * 8;
    float4 a = *(const float4*)s;
    float4 b = *(const float4*)(s + 4);
    ushort8 r;
    r[0] = f32_bf16(a.x); r[1] = f32_bf16(a.y);
    r[2] = f32_bf16(a.z); r[3] = f32_bf16(a.w);
    r[4] = f32_bf16(b.x); r[5] = f32_bf16(b.y);
    r[6] = f32_bf16(b.z); r[7] = f32_bf16(b.w);
    *(ushort8*)(W2 + (size_t)o * 2048 + e * 512 + i8 * 8) = r;
  }
}

// ---------------------------------------------------------------------------
// gemm_bt: 128x128 tile, BK=32, 512 threads / 8 waves. Triple-buffered,
// counted vmcnt(2). (Unchanged from round 6/7 — passing.)
// ---------------------------------------------------------------------------
template <int MODE>
__global__ __launch_bounds__(512, 2)
void gemm_bt(const unsigned short* __restrict__ A,
             const unsigned short* __restrict__ Bm,
             void* __restrict__ Out, const float* __restrict__ bias,
             const float* __restrict__ S,
             int lda, int ldb, int ldo, int K, int Ediv,
             long sAb, long sAe, long sBb, long sBe, long sOb, long sOe) {
  __shared__ __align__(16) char ldsRaw[49152];
  char* ldsg = ldsRaw;
  const unsigned ldsb =
      (unsigned)(unsigned long long)(__attribute__((address_space(3))) char*)(void*)ldsRaw;

  const int u = threadIdx.x;
  const int z = blockIdx.z;
  const int zb = z / Ediv, ze = z % Ediv;
  const unsigned short* Ab = A  + zb * sAb + ze * sAe + (long)(blockIdx.y * 128) * lda;
  const unsigned short* Bb = Bm + zb * sBb + ze * sBe + (long)(blockIdx.x * 128) * ldb;

  const unsigned short* gA = Ab + (long)(u >> 2) * lda + (u & 3) * 8;
  const unsigned short* gB = Bb + (long)(u >> 2) * ldb + (u & 3) * 8;

  const int w = u >> 6, lane = u & 63;
  const int wm = (w & 1) * 64, wn = (w >> 1) * 32;
  const int fm = lane & 15, fk = (lane >> 4) * 8;
  const unsigned aF = (unsigned)((wm + fm) * 64 + fk * 2);
  const unsigned bF = 24576u + (unsigned)((wn + fm) * 64 + fk * 2);
  const unsigned u16 = (unsigned)(u * 16);

  f32x4 acc[4][2] = {};

  const int nt = K / 32;
#define STGBT(buf, kk) do { \
    gl2lds16(gA + (kk) * 32, ldsg + (buf) * 8192 + u16); \
    gl2lds16(gB + (kk) * 32, ldsg + 24576 + (buf) * 8192 + u16); } while (0)

  STGBT(0, 0);
  STGBT(1, 1);
  asm volatile("s_waitcnt vmcnt(2)" ::: "memory");
  __builtin_amdgcn_s_barrier();

  int cur = 0, pre = 2;
  for (int t = 0; t < nt; ++t) {
    bf16x8 af[4], bfv[2];
    const unsigned cb = (unsigned)(cur * 8192);
#pragma unroll
    for (int i = 0; i < 4; i++) DSR(af[i], ldsb + cb + aF + (unsigned)(i * 1024));
#pragma unroll
    for (int j = 0; j < 2; j++) DSR(bfv[j], ldsb + cb + bF + (unsigned)(j * 1024));
    const int kk = (t + 2 < nt) ? t + 2 : nt - 1;
    STGBT(pre, kk);
    asm volatile("s_waitcnt lgkmcnt(0)" ::: "memory");
    __builtin_amdgcn_sched_barrier(0);
    __builtin_amdgcn_s_setprio(1);
#pragma unroll
    for (int i = 0; i < 4; i++)
#pragma unroll
      for (int j = 0; j < 2; j++)
        acc[i][j] = __builtin_amdgcn_mfma_f32_16x16x32_bf16(af[i], bfv[j],
                                                            acc[i][j], 0, 0, 0);
    __builtin_amdgcn_s_setprio(0);
    asm volatile("s_waitcnt vmcnt(2)" ::: "memory");
    __builtin_amdgcn_sched_barrier(0);
    __builtin_amdgcn_s_barrier();
    cur = (cur == 2) ? 0 : cur + 1;
    pre = (pre == 2) ? 0 : pre + 1;
  }
#undef STGBT
  asm volatile("s_waitcnt vmcnt(0)" ::: "memory");

  const long ob = zb * sOb + ze * sOe;
  const int em0 = blockIdx.y * 128 + wm + ((lane >> 4) << 2);
  const int en0 = blockIdx.x * 128 + wn + fm;
  float bcol[2];
  if (MODE == 1) {
#pragma unroll
    for (int j = 0; j < 2; j++) bcol[j] = bias[en0 + j * 16];
  }
#pragma unroll
  for (int i = 0; i < 4; i++)
#pragma unroll
    for (int r = 0; r < 4; r++) {
      const int m = em0 + i * 16 + r;
      const float sm = (MODE == 1) ? S[m] : 0.0f;
#pragma unroll
      for (int j = 0; j < 2; j++) {
        const long off = ob + (long)m * ldo + en0 + j * 16;
        if (MODE == 1)
          ((float*)Out)[off] = acc[i][j][r] + sm * bcol[j];
        else
          ((unsigned short*)Out)[off] = f32_bf16(acc[i][j][r]);
      }
    }
}

// ---------------------------------------------------------------------------
// gemm256 v3: B direct-from-L2 (LDS-port relief), hardened after v2's failure.
//  - B fragment loads are PLAIN C++ loads (compiler-managed waits/spills).
//  - A fragment reads are PLAIN &lds[...] loads (ds_read, compiler lgkmcnt).
//  - ONE manual sync per K-tile (only the gl2lds->ds_read dep the compiler
//    can't see):  LOADB(kt+1) -> vmcnt(12) -> s_barrier -> STGA(kt+2) -> compute.
//  Ledger (steady): outstanding at vmcnt = [STGA(kt)4, B(kt)8, STGA(kt+1)4,
//  B(kt+1)8] = 24 -> vmcnt(12) drains exactly STGA(kt)+B(kt). Plain loads
//  cannot cross the memory-clobber asm or s_barrier, so region counts are
//  exact. Stage-after-barrier: target buf (kt+2)%3's readers (phase kt-1)
//  are sealed by the barrier just crossed. 3 A buffers x 32 KiB = 96 KiB.
//  Tail: stage kk clamped to 31; last LOADB reads dead-but-valid bytes.
// ---------------------------------------------------------------------------
__global__ __launch_bounds__(512, 2)
void gemm256(const unsigned short* __restrict__ A,
             const unsigned short* __restrict__ Bm,
             float* __restrict__ Out,
             const float* __restrict__ bias,
             const float* __restrict__ S) {
  __shared__ __align__(16) unsigned short lds[49152];  // 96 KiB: 3 A buffers
  char* ldsg = (char*)lds;

  const int bid = blockIdx.x;
  const int bx = (bid & 7) * 4 + ((bid >> 3) & 3);   // N tile 0..31 (4/XCD)
  const int by = bid >> 5;                           // M tile 0..15

  const int u = threadIdx.x;
  const int w = u >> 6, lane = u & 63;
  const unsigned w1024 = (unsigned)(w * 1024);
  const int wmw = (w >> 2) * 128;      // wave M offset in tile
  const int wnw = (w & 3) * 64;        // wave N offset in tile
  const int fm = lane & 15;

  // A read-side swizzled bases (byte ^= ((row&7)<<4))
  const unsigned hi16  = (unsigned)((lane >> 4) * 16);
  const unsigned xorv  = (unsigned)((fm & 7) << 4);
  const unsigned aR0 = (unsigned)((wmw + fm) * 128) + (hi16 ^ xorv);
  const unsigned aR1 = aR0 ^ 64u;

  // A stage-side: linear LDS dest, pre-swizzled global source
  const int srr = w * 8 + (lane >> 3);
  const unsigned swzS = (unsigned)((((lane & 7) ^ ((lane >> 3) & 7)) << 4));
  const char* gA = (const char*)(A + (size_t)(by * 256) * 2048)
                   + (size_t)srr * 4096 + swzS;

  // B direct row pointers (bytes): row = bx*256 + wnw + j*16 + fm; +hi16 frag col
  const char* pB0 = (const char*)Bm + (size_t)(bx * 256 + wnw +  0 + fm) * 4096 + hi16;
  const char* pB1 = (const char*)Bm + (size_t)(bx * 256 + wnw + 16 + fm) * 4096 + hi16;
  const char* pB2 = (const char*)Bm + (size_t)(bx * 256 + wnw + 32 + fm) * 4096 + hi16;
  const char* pB3 = (const char*)Bm + (size_t)(bx * 256 + wnw + 48 + fm) * 4096 + hi16;

#define STGA(kk, loff) do { const char* _s = gA + (kk) * 128; \
    gl2lds16(_s,          ldsg + (loff) + w1024); \
    gl2lds16(_s + 262144, ldsg + (loff) + 8192  + w1024); \
    gl2lds16(_s + 524288, ldsg + (loff) + 16384 + w1024); \
    gl2lds16(_s + 786432, ldsg + (loff) + 24576 + w1024); } while (0)

#define LOADB(BQ, ko) do { \
    BQ[0][0] = *(const bf16x8*)(pB0 + (ko)); BQ[0][1] = *(const bf16x8*)(pB0 + (ko) + 64); \
    BQ[1][0] = *(const bf16x8*)(pB1 + (ko)); BQ[1][1] = *(const bf16x8*)(pB1 + (ko) + 64); \
    BQ[2][0] = *(const bf16x8*)(pB2 + (ko)); BQ[2][1] = *(const bf16x8*)(pB2 + (ko) + 64); \
    BQ[3][0] = *(const bf16x8*)(pB3 + (ko)); BQ[3][1] = *(const bf16x8*)(pB3 + (ko) + 64); } while (0)

  // sub-phase: 4 plain A ds_reads + 16 MFMA; compiler manages lgkmcnt
#define SUBPH(bufS, mh, kh, BQ) do { \
    bf16x8 av_[4]; \
    _Pragma("unroll") \
    for (int i = 0; i < 4; ++i) \
      av_[i] = *(const bf16x8*)&lds[((bufS) + ((kh) ? aR1 : aR0) \
                                     + (unsigned)(((mh) * 4 + i) * 2048)) >> 1]; \
    __builtin_amdgcn_s_setprio(1); \
    _Pragma("unroll") \
    for (int i = 0; i < 4; ++i) { \
      _Pragma("unroll") \
      for (int j = 0; j < 4; ++j) \
        acc[(mh) * 4 + i][j] = __builtin_amdgcn_mfma_f32_16x16x32_bf16( \
            av_[i], BQ[j][kh], acc[(mh) * 4 + i][j], 0, 0, 0); \
    } \
    __builtin_amdgcn_s_setprio(0); \
  } while (0)

  bf16x8 bqE[4][2], bqO[4][2];
  f32x4 acc[8][4] = {};

  // prologue: A(0)->buf0, A(1)->buf1, B(0)->bqE; drain all
  STGA(0, 0u);
  STGA(1, 32768u);
  LOADB(bqE, 0);
  asm volatile("s_waitcnt vmcnt(0)" ::: "memory");
  __builtin_amdgcn_s_barrier();

  int c0 = 0;   // (2t)%3
  for (int t = 0; t < 16; ++t) {
    const int c1 = (c0 + 1 == 3) ? 0 : c0 + 1;
    const int c2 = (c1 + 1 == 3) ? 0 : c1 + 1;
    const unsigned bufE = (unsigned)(c0 * 32768);
    const unsigned bufO = (unsigned)(c1 * 32768);
    const int kE = (2 * t + 2 < 32) ? 2 * t + 2 : 31;   // even-phase stage kt
    const int kO = (2 * t + 3 < 32) ? 2 * t + 3 : 31;   // odd-phase stage kt

    // ---- even kt = 2t: A from buf c0, B regs bqE ----
    LOADB(bqO, 128);                                     // B(2t+1)
    asm volatile("s_waitcnt vmcnt(12)" ::: "memory");    // drains STGA(2t)+B(2t)
    __builtin_amdgcn_s_barrier();
    STGA(kE, (unsigned)(c2 * 32768));                    // A(2t+2) -> buf c2
    SUBPH(bufE, 0, 0, bqE);
    SUBPH(bufE, 0, 1, bqE);
    SUBPH(bufE, 1, 0, bqE);
    SUBPH(bufE, 1, 1, bqE);

    // ---- odd kt = 2t+1: A from buf c1, B regs bqO ----
    LOADB(bqE, 256);                                     // B(2t+2)
    asm volatile("s_waitcnt vmcnt(12)" ::: "memory");    // drains STGA(2t+1)+B(2t+1)
    __builtin_amdgcn_s_barrier();
    STGA(kO, (unsigned)(c0 * 32768));                    // A(2t+3) -> buf c0
    SUBPH(bufO, 0, 0, bqO);
    SUBPH(bufO, 0, 1, bqO);
    SUBPH(bufO, 1, 0, bqO);
    SUBPH(bufO, 1, 1, bqO);

    c0 = c2;
    pB0 += 256; pB1 += 256; pB2 += 256; pB3 += 256;
  }
#undef SUBPH
#undef LOADB
#undef STGA
  asm volatile("s_waitcnt vmcnt(0)" ::: "memory");  // drain tail stages

  // epilogue: C/D layout col=lane&15, row=(lane>>4)*4+reg  [m89/m91]
  const int m0 = by * 256 + wmw + ((lane >> 4) << 2);
  const int n0 = bx * 256 + wnw + (lane & 15);
  float bc[4];
#pragma unroll
  for (int j = 0; j < 4; ++j) bc[j] = bias[n0 + j * 16];
#pragma unroll
  for (int i = 0; i < 8; ++i)
#pragma unroll
    for (int r = 0; r < 4; ++r) {
      const int m = m0 + i * 16 + r;
      const float sm = S[m];
#pragma unroll
      for (int j = 0; j < 4; ++j)
        Out[(size_t)m * 8192 + n0 + j * 16] = acc[i][j][r] + sm * bc[j];
    }
}

// ---------------------------------------------------------------------------
// launch
// ---------------------------------------------------------------------------
extern "C" void kernel_launch(void* const* d_in, const int* in_sizes, int n_in,
                              void* d_out, int out_size, void* d_ws,
                              size_t ws_size, hipStream_t stream) {
  (void)in_sizes; (void)n_in; (void)out_size; (void)ws_size;
  const float* x       = (const float*)d_in[0];  // (B,T,IN)
  const float* combine = (const float*)d_in[1];  // (B,T,E,C)
  const float* mask    = (const float*)d_in[2];  // (B,T,E,C)
  const float* weight  = (const float*)d_in[3];  // (OUT,IN)
  const float* bias    = (const float*)d_in[4];  // (OUT,)
  float* out = (float*)d_out;                    // (B,T,OUT) fp32

  // workspace layout (~105 MB)
  char* ws = (char*)d_ws;
  unsigned short* W2      = (unsigned short*)ws;                    // 32 MB
  unsigned short* comb_bf = (unsigned short*)(ws + 33554432);       // 16 MB
  float*          S       = (float*)(ws + 50331648);                // 16 KB
  unsigned short* xT      = (unsigned short*)(ws + 51380224);       // 16 MB
  unsigned short* maskT   = (unsigned short*)(ws + 68157440);       // 16 MB
  unsigned short* xdT     = (unsigned short*)(ws + 84934656);       //  8 MB
  unsigned short* zbuf    = (unsigned short*)(ws + 93323264);       // 16 MB

  // 0) all layout/dtype prep in ONE launch
  prep<<<16384, 256, 0, stream>>>(x, mask, combine, weight, xT, maskT,
                                  comb_bf, S, W2);

  // 1) xdT[b,e,i,c] = sum_t xT[b,e,i,t] * maskT[b,e,c,t]
  gemm_bt<0><<<dim3(4, 4, 16), 512, 0, stream>>>(
      xT, maskT, (void*)xdT, nullptr, nullptr, 1024, 1024, 512, 1024,
      4, 2097152L, 524288L, 2097152L, 524288L, 1048576L, 262144L);

  // 2) z[b,t,(e,i)] = sum_c comb_bf[b,t,e,c] * xdT[b,e,i,c]
  gemm_bt<0><<<dim3(4, 8, 16), 512, 0, stream>>>(
      comb_bf, xdT, (void*)zbuf, nullptr, nullptr, 2048, 512, 2048, 512,
      4, 2097152L, 512L, 1048576L, 262144L, 2097152L, 512L);

  // 3) out[m,o] = sum_{(e,i)} z[m,(e,i)] * W2[o,(e,i)] + S[m]*bias[o]
  //    M=4096 N=8192 K=2048 — A-in-LDS(x3) + B-direct-from-L2 (v3, hardened)
  gemm256<<<dim3(512), 512, 0, stream>>>(zbuf, W2, out, bias, S);
}